// Round 1
// baseline (343.857 us; speedup 1.0000x reference)
//
#include <hip/hip_runtime.h>

#define BB 32
#define LL 512
#define EMB 128
#define RS 11
#define RR 5

typedef float f4 __attribute__((ext_vector_type(4)));

__global__ __launch_bounds__(256) void region_encoder_kernel(
    const int* __restrict__ seq,
    const float* __restrict__ W,
    const float* __restrict__ U,
    float* __restrict__ out)
{
    // Block handles 8 consecutive rows (8 | 512, so all share the same b).
    // 32 lanes per output row; each lane owns one float4 (128 floats / row).
    const int row0 = blockIdx.x * 8;
    const int b    = row0 >> 9;       // row / 512
    const int l0   = row0 & 511;      // row % 512

    // Stage the 18 window tokens (positions l0-5 .. l0+12) in LDS ONCE.
    // This removes the per-row dependent seq->U load chain: every thread's
    // 11 U gather addresses become computable from a broadcast LDS read.
    __shared__ int toks[RS + 8 - 1];  // 18
    if (threadIdx.x < RS + 8 - 1) {
        const int p = l0 - RR + (int)threadIdx.x;
        toks[threadIdx.x] = (p >= 0 && p < LL) ? seq[(b << 9) + p] : 0;
    }
    __syncthreads();

    const int r    = threadIdx.x >> 5;   // sub-row 0..7
    const int lane = threadIdx.x & 31;
    const int row  = row0 + r;

    // Token for this output row: position l0+r -> toks[r + RR].
    const int s = toks[r + RR];

    const f4* W4 = (const f4*)(W + (size_t)s * EMB);
    const f4  t  = W4[lane];             // issue early; L3-resident after warmup

    f4 m = (f4){-INFINITY, -INFINITY, -INFINITY, -INFINITY};

    // All 11 U gathers issue immediately (addresses from LDS broadcast).
    // NOT nontemporal: the unique working set (~79 MB of U rows + ~7 MB of W)
    // fits in the 256 MB Infinity Cache; intra-launch duplicate tokens and
    // cross-replay re-reads should hit L3 instead of HBM.
    #pragma unroll
    for (int j = 0; j < RS; ++j) {
        const int w = toks[r + j];       // token at position l0 + r + j - RR
        const f4* U4 = (const f4*)(U + (size_t)(w * RS + j) * EMB);
        const f4 u = U4[lane];
        m.x = fmaxf(m.x, u.x * t.x);
        m.y = fmaxf(m.y, u.y * t.y);
        m.z = fmaxf(m.z, u.z * t.z);
        m.w = fmaxf(m.w, u.w * t.w);
    }

    f4 res;
    if (s != 0) {
        res = m;
    } else {
        res = (f4){0.f, 0.f, 0.f, 0.f};
    }
    // Output is never re-read: keep the nontemporal store.
    __builtin_nontemporal_store(res, (f4*)(out + (size_t)row * EMB) + lane);
}

extern "C" void kernel_launch(void* const* d_in, const int* in_sizes, int n_in,
                              void* d_out, int out_size, void* d_ws, size_t ws_size,
                              hipStream_t stream)
{
    const int*   seq = (const int*)  d_in[0];   // (B, L, 1) int32
    const float* W   = (const float*)d_in[1];   // (VOCAB, EMB) f32
    const float* U   = (const float*)d_in[2];   // (VOCAB*RS, EMB) f32
    float* out = (float*)d_out;                 // (B, L, 1, EMB) f32

    const int rows = BB * LL;                   // 16384
    const int blocks = rows / 8;                // 2048 blocks of 256 threads
    region_encoder_kernel<<<blocks, 256, 0, stream>>>(seq, W, U, out);
}